// Round 1
// baseline (73.940 us; speedup 1.0000x reference)
//
#include <hip/hip_runtime.h>

// Problem constants
#define BB 16
#define CC 64
#define DD 16
#define HW 2304   // 48*48
#define HID 16
#define NEG_SLOPE 0.01f

// Kernel 1: one block per (b,d). 1024 threads = 16 waves; each wave reduces
// 4 channel planes (2304 fp32 each, as 576 float4 -> 9 float4/lane), then the
// tiny 64->16->64 MLP + sigmoid runs in LDS. Gate written to workspace.
__global__ __launch_bounds__(1024) void gate_kernel(
    const float* __restrict__ x,
    const float* __restrict__ w1, const float* __restrict__ b1,
    const float* __restrict__ w2, const float* __restrict__ b2,
    float* __restrict__ gate)
{
    const int bd = blockIdx.x;
    const int b = bd / DD, d = bd % DD;
    const int wave = threadIdx.x >> 6;
    const int lane = threadIdx.x & 63;

    __shared__ float pooled[CC];
    __shared__ float hbuf[HID];

    #pragma unroll
    for (int i = 0; i < 4; ++i) {
        const int c = wave * 4 + i;
        const float4* p = (const float4*)(x + (((size_t)(b * CC + c) * DD + d) * HW));
        float s = 0.f;
        #pragma unroll
        for (int j = 0; j < 9; ++j) {
            float4 v = p[lane + j * 64];
            s += v.x + v.y + v.z + v.w;
        }
        #pragma unroll
        for (int m = 32; m; m >>= 1) s += __shfl_xor(s, m, 64);
        if (lane == 0) pooled[c] = s * (1.0f / HW);
    }
    __syncthreads();

    if (threadIdx.x < HID) {
        float acc = b1[threadIdx.x];
        #pragma unroll
        for (int c = 0; c < CC; ++c) acc += w1[threadIdx.x * CC + c] * pooled[c];
        hbuf[threadIdx.x] = acc >= 0.f ? acc : NEG_SLOPE * acc;
    }
    __syncthreads();

    if (threadIdx.x < CC) {
        float acc = b2[threadIdx.x];
        #pragma unroll
        for (int o = 0; o < HID; ++o) acc += w2[threadIdx.x * HID + o] * hbuf[o];
        float g = 1.0f / (1.0f + __expf(-acc));
        gate[(b * CC + threadIdx.x) * DD + d] = g;
    }
}

// Kernel 2: float4 grid-stride broadcast multiply. 4 consecutive floats share
// one gate value (2304 % 4 == 0), gate index = float4_index / 576.
__global__ __launch_bounds__(256) void mul_kernel(
    const float* __restrict__ x,
    const float* __restrict__ gate,
    float* __restrict__ out)
{
    const int N4 = BB * CC * DD * HW / 4;  // 9,437,184
    const int stride = gridDim.x * blockDim.x;
    for (int i = blockIdx.x * blockDim.x + threadIdx.x; i < N4; i += stride) {
        const int g = i / 576;
        const float gv = gate[g];
        float4 v = ((const float4*)x)[i];
        v.x *= gv; v.y *= gv; v.z *= gv; v.w *= gv;
        ((float4*)out)[i] = v;
    }
}

extern "C" void kernel_launch(void* const* d_in, const int* in_sizes, int n_in,
                              void* d_out, int out_size, void* d_ws, size_t ws_size,
                              hipStream_t stream) {
    const float* x  = (const float*)d_in[0];
    const float* w1 = (const float*)d_in[1];
    const float* b1 = (const float*)d_in[2];
    const float* w2 = (const float*)d_in[3];
    const float* b2 = (const float*)d_in[4];
    float* out  = (float*)d_out;
    float* gate = (float*)d_ws;   // B*C*D = 16384 floats = 64 KB

    gate_kernel<<<BB * DD, 1024, 0, stream>>>(x, w1, b1, w2, b2, gate);
    mul_kernel<<<2048, 256, 0, stream>>>(x, gate, out);
}

// Round 2
// 56.408 us; speedup vs baseline: 1.3108x; 1.3108x over previous
//
#include <hip/hip_runtime.h>

#define BB 16
#define CC 64
#define DD 16
#define HW 2304     // 48*48
#define HID 16
#define NEG_SLOPE 0.01f

#define NREG 5      // float4/channel kept in registers (j = 0..4)
#define NLDS 2      // float4/channel kept in LDS       (j = 5..6)
#define NRER 2      // float4/channel re-read from LLC  (j = 7..8)
#define CH_STRIDE4 (DD * HW / 4)   // 9216 float4 between channels at fixed (b,d)

using f4 = __attribute__((ext_vector_type(4))) float;

// One block per (b,d). 16 waves x 4 channels each. Pool -> tiny MLP gate in
// LDS -> multiply, with 7/9 of the slice held on-chip (regs + LDS) so x is
// read from HBM essentially once. Non-temporal out stores keep x LLC-resident.
__global__ __launch_bounds__(1024) void fused_se_kernel(
    const float* __restrict__ x,
    const float* __restrict__ w1, const float* __restrict__ b1,
    const float* __restrict__ w2, const float* __restrict__ b2,
    float* __restrict__ out)
{
    const int bd   = blockIdx.x;
    const int b    = bd >> 4;
    const int d    = bd & 15;
    const int tid  = threadIdx.x;
    const int wave = tid >> 6;
    const int lane = tid & 63;

    __shared__ f4 stage[4 * NLDS][1024];   // 128 KiB, wave-contiguous layout
    __shared__ float pooled[CC];
    __shared__ float hbuf[HID];
    __shared__ float gate_s[CC];

    // base float4 index for (b, c=0, d); per-lane offset
    const size_t base4 = ((size_t)(b * CC) * DD + d) * (HW / 4);
    const f4* xp = (const f4*)x + base4 + lane;

    f4 rv[4][NREG];
    float csum[4];

    #pragma unroll
    for (int i = 0; i < 4; ++i) {
        const int c = wave * 4 + i;
        const f4* p = xp + (size_t)c * CH_STRIDE4;
        float s = 0.f;
        #pragma unroll
        for (int j = 0; j < NREG; ++j) {
            f4 v = p[j * 64];
            rv[i][j] = v;
            s += v.x + v.y + v.z + v.w;
        }
        #pragma unroll
        for (int k = 0; k < NLDS; ++k) {
            f4 v = p[(NREG + k) * 64];
            stage[i * NLDS + k][tid] = v;
            s += v.x + v.y + v.z + v.w;
        }
        #pragma unroll
        for (int k = 0; k < NRER; ++k) {
            f4 v = p[(NREG + NLDS + k) * 64];
            s += v.x + v.y + v.z + v.w;
        }
        #pragma unroll
        for (int m = 32; m; m >>= 1) s += __shfl_xor(s, m, 64);
        csum[i] = s;
    }
    if (lane == 0) {
        #pragma unroll
        for (int i = 0; i < 4; ++i) pooled[wave * 4 + i] = csum[i] * (1.0f / HW);
    }
    __syncthreads();

    if (tid < HID) {
        float acc = b1[tid];
        #pragma unroll
        for (int c = 0; c < CC; ++c) acc += w1[tid * CC + c] * pooled[c];
        hbuf[tid] = acc >= 0.f ? acc : NEG_SLOPE * acc;
    }
    __syncthreads();
    if (tid < CC) {
        float acc = b2[tid];
        #pragma unroll
        for (int o = 0; o < HID; ++o) acc += w2[tid * HID + o] * hbuf[o];
        gate_s[tid] = 1.0f / (1.0f + expf(-acc));
    }
    __syncthreads();

    f4* op = (f4*)out + base4 + lane;
    #pragma unroll
    for (int i = 0; i < 4; ++i) {
        const int c = wave * 4 + i;
        const float gv = gate_s[c];
        f4* q       = op + (size_t)c * CH_STRIDE4;
        const f4* p = xp + (size_t)c * CH_STRIDE4;
        #pragma unroll
        for (int j = 0; j < NREG; ++j) {
            f4 v = rv[i][j];
            v.x *= gv; v.y *= gv; v.z *= gv; v.w *= gv;
            __builtin_nontemporal_store(v, q + j * 64);
        }
        #pragma unroll
        for (int k = 0; k < NLDS; ++k) {
            f4 v = stage[i * NLDS + k][tid];
            v.x *= gv; v.y *= gv; v.z *= gv; v.w *= gv;
            __builtin_nontemporal_store(v, q + (NREG + k) * 64);
        }
        #pragma unroll
        for (int k = 0; k < NRER; ++k) {
            f4 v = p[(NREG + NLDS + k) * 64];   // LLC-hot re-read
            v.x *= gv; v.y *= gv; v.z *= gv; v.w *= gv;
            __builtin_nontemporal_store(v, q + (NREG + NLDS + k) * 64);
        }
    }
}

extern "C" void kernel_launch(void* const* d_in, const int* in_sizes, int n_in,
                              void* d_out, int out_size, void* d_ws, size_t ws_size,
                              hipStream_t stream) {
    const float* x  = (const float*)d_in[0];
    const float* w1 = (const float*)d_in[1];
    const float* b1 = (const float*)d_in[2];
    const float* w2 = (const float*)d_in[3];
    const float* b2 = (const float*)d_in[4];
    float* out = (float*)d_out;

    fused_se_kernel<<<BB * DD, 1024, 0, stream>>>(x, w1, b1, w2, b2, out);
}